// Round 3
// baseline (874.249 us; speedup 1.0000x reference)
//
#include <hip/hip_runtime.h>
#include <math.h>

#define HD 16   // hidden dim
#define NC 4    // num classes
#define NIV 17  // intervals = HD + 1

// ---------- K_thr: single-thread threshold prep (tiny) ----------
// ts[16]: sorted relu-flip thresholds t_f = -b1/W1.
// masks[f]: 17-bit interval-activity mask for feature f.
__global__ void k_thr(const float* __restrict__ W1, const float* __restrict__ b1,
                      float* __restrict__ ts, unsigned* __restrict__ masks) {
    if (threadIdx.x != 0 || blockIdx.x != 0) return;
    float t[HD], s[HD];
    for (int f = 0; f < HD; ++f) {
        float w = W1[f];
        t[f] = (w != 0.0f) ? (-b1[f] / w) : INFINITY;
        s[f] = t[f];
    }
    // insertion sort (16 elements)
    for (int i = 1; i < HD; ++i) {
        float key = s[i]; int j = i - 1;
        while (j >= 0 && s[j] > key) { s[j + 1] = s[j]; --j; }
        s[j + 1] = key;
    }
    for (int f = 0; f < HD; ++f) ts[f] = s[f];
    for (int f = 0; f < HD; ++f) {
        float w = W1[f];
        unsigned m;
        if (w == 0.0f) {
            m = (b1[f] > 0.0f) ? 0x1FFFFu : 0u;  // relu(b1) constant
        } else {
            int c = 0;  // #{thresholds < t_f}
            for (int g = 0; g < HD; ++g) c += (s[g] < t[f]) ? 1 : 0;
            if (w > 0.0f) m = 0x1FFFFu & ~((1u << (c + 1)) - 1u);  // buckets > c
            else          m = (1u << (c + 1)) - 1u;                // buckets <= c
        }
        masks[f] = m;
    }
}

// ---------- K1: in-degree histogram ----------
__global__ void k_degree(const int* __restrict__ col, int* __restrict__ cnt, int E) {
    int i = blockIdx.x * blockDim.x + threadIdx.x;
    if (i < E) atomicAdd(&cnt[col[i]], 1);
}

// ---------- K2: dinv = rsqrt(deg+1); dx = dinv*x ----------
__global__ void k_dinv(const int* __restrict__ cnt, const float* __restrict__ x,
                       float* __restrict__ dinv, float* __restrict__ dx, int N) {
    int i = blockIdx.x * blockDim.x + threadIdx.x;
    if (i < N) {
        float d = rsqrtf((float)(cnt[i] + 1));
        dinv[i] = d;
        dx[i] = d * x[i];
    }
}

// ---------- K3: layer-1 scalar scatter: t1[c] += dx[r] ----------
__global__ void k_l1(const int* __restrict__ row, const int* __restrict__ col,
                     const float* __restrict__ dx, float* __restrict__ t1, int E) {
    int i = blockIdx.x * blockDim.x + threadIdx.x;
    if (i < E) unsafeAtomicAdd(&t1[col[i]], dx[row[i]]);
}

// ---------- K4: finalize s1; pack (dinv, s1) for the 8B gather ----------
__global__ void k_s1(const float* __restrict__ t1, const float* __restrict__ dinv,
                     const float* __restrict__ dx, float2* __restrict__ ds, int N) {
    int i = blockIdx.x * blockDim.x + threadIdx.x;
    if (i < N) {
        float d = dinv[i];
        float s = d * (t1[i] + dx[i]);  // + self-loop dinv^2 * x
        ds[i] = make_float2(d, s);
    }
}

// ---------- K5: bucketed layer-2 scatter: 2 atomics/edge ----------
__global__ void k_edge2(const int* __restrict__ row, const int* __restrict__ col,
                        const float2* __restrict__ ds, const float* __restrict__ ts,
                        float* __restrict__ PQ, int E) {
    float tsr[HD];
    #pragma unroll
    for (int g = 0; g < HD; ++g) tsr[g] = ts[g];
    int stride = gridDim.x * blockDim.x;
    for (int e = blockIdx.x * blockDim.x + threadIdx.x; e < E; e += stride) {
        int r = row[e], c = col[e];
        float2 d = ds[r];
        float dv = d.x, sv = d.y;
        int b = 0;
        #pragma unroll
        for (int g = 0; g < HD; ++g) b += (sv > tsr[g]) ? 1 : 0;
        float* base = PQ + (size_t)c * (2 * NIV) + 2 * b;
        unsafeAtomicAdd(base, dv * sv);      // P
        unsafeAtomicAdd(base + 1, dv);       // Q
    }
}

// ---------- K6: per-node reconstruction + W2/relu + Wfc epilogue ----------
__global__ void k_final(const float* __restrict__ PQ, const float2* __restrict__ ds,
                        const float* __restrict__ W1, const float* __restrict__ b1,
                        const unsigned* __restrict__ masks,
                        const float* __restrict__ W2, const float* __restrict__ b2,
                        const float* __restrict__ Wfc, const float* __restrict__ bfc,
                        float* __restrict__ out, int N) {
    int i = blockIdx.x * blockDim.x + threadIdx.x;
    if (i >= N) return;
    float2 dsi = ds[i];
    float di = dsi.x, si = dsi.y;
    const float* base = PQ + (size_t)i * (2 * NIV);
    float P[NIV], Q[NIV];
    #pragma unroll
    for (int m = 0; m < NIV; ++m) { P[m] = base[2 * m]; Q[m] = base[2 * m + 1]; }
    float agg[HD];
    #pragma unroll
    for (int f = 0; f < HD; ++f) {
        unsigned mk = masks[f];
        float w = W1[f], bb = b1[f];
        float A = 0.0f, B = 0.0f;
        #pragma unroll
        for (int m = 0; m < NIV; ++m) {
            if ((mk >> m) & 1u) { A += P[m]; B += Q[m]; }
        }
        float h1i = fmaxf(fmaf(w, si, bb), 0.0f);         // exact self term
        agg[f] = di * (fmaf(w, A, bb * B) + di * h1i);
    }
    float o0 = bfc[0], o1 = bfc[1], o2 = bfc[2], o3 = bfc[3];
    #pragma unroll
    for (int f2 = 0; f2 < HD; ++f2) {
        float h = b2[f2];
        #pragma unroll
        for (int k = 0; k < HD; ++k) h = fmaf(agg[k], W2[k * HD + f2], h);
        h = fmaxf(h, 0.0f);
        o0 = fmaf(h, Wfc[f2 * NC + 0], o0);
        o1 = fmaf(h, Wfc[f2 * NC + 1], o1);
        o2 = fmaf(h, Wfc[f2 * NC + 2], o2);
        o3 = fmaf(h, Wfc[f2 * NC + 3], o3);
    }
    ((float4*)out)[i] = make_float4(o0, o1, o2, o3);
}

extern "C" void kernel_launch(void* const* d_in, const int* in_sizes, int n_in,
                              void* d_out, int out_size, void* d_ws, size_t ws_size,
                              hipStream_t stream) {
    const float* x   = (const float*)d_in[0];
    const int*   ei  = (const int*)d_in[1];
    const float* W1  = (const float*)d_in[2];
    const float* b1  = (const float*)d_in[3];
    const float* W2  = (const float*)d_in[4];
    const float* b2  = (const float*)d_in[5];
    const float* Wfc = (const float*)d_in[6];
    const float* bfc = (const float*)d_in[7];
    float* out = (float*)d_out;

    const int N = in_sizes[0];
    const int E = in_sizes[1] / 2;
    const int* row = ei;
    const int* col = ei + E;

    // workspace layout (all offsets in floats/ints of 4B)
    // zero-region (one memset): [cnt N][t1 N][PQ 34N]  = 36N*4 bytes
    char* ws = (char*)d_ws;
    int*    cnt  = (int*)ws;                                  // N
    float*  t1   = (float*)(ws + (size_t)N * 4);              // N
    float*  PQ   = (float*)(ws + (size_t)N * 8);              // 34N
    float*  dinv = (float*)(ws + (size_t)N * 4 * 36);         // N
    float*  dx   = (float*)(ws + (size_t)N * 4 * 37);         // N
    float2* ds   = (float2*)(ws + (size_t)N * 4 * 38);        // 2N
    float*  ts   = (float*)(ws + (size_t)N * 4 * 40);         // 16
    unsigned* masks = (unsigned*)(ws + (size_t)N * 4 * 40 + 64); // 16

    hipMemsetAsync(ws, 0, (size_t)N * 4 * 36, stream);  // cnt + t1 + PQ

    const int B = 256;
    k_thr<<<1, 64, 0, stream>>>(W1, b1, ts, masks);
    k_degree<<<(E + B - 1) / B, B, 0, stream>>>(col, cnt, E);
    k_dinv<<<(N + B - 1) / B, B, 0, stream>>>(cnt, x, dinv, dx, N);
    k_l1<<<(E + B - 1) / B, B, 0, stream>>>(row, col, dx, t1, E);
    k_s1<<<(N + B - 1) / B, B, 0, stream>>>(t1, dinv, dx, ds, N);
    k_edge2<<<2048, B, 0, stream>>>(row, col, ds, ts, PQ, E);
    k_final<<<(N + B - 1) / B, B, 0, stream>>>(PQ, ds, W1, b1, masks,
                                               W2, b2, Wfc, bfc, out, N);
}

// Round 4
// 579.949 us; speedup vs baseline: 1.5075x; 1.5075x over previous
//
#include <hip/hip_runtime.h>

#define HD 16    // hidden dim
#define NC 4     // num classes
#define BSH 9    // log2(nodes per bucket)
#define BSZ 512  // nodes per bucket
#define MAXB 512 // max buckets (needs N <= 2^18 so src fits 18 bits)

// ---------- per-bucket edge count (streaming, LDS histogram) ----------
__global__ void k_count(const int* __restrict__ col, int* __restrict__ gcount,
                        int E, int NB) {
    __shared__ int hist[MAXB];
    int t = threadIdx.x;
    for (int i = t; i < MAXB; i += blockDim.x) hist[i] = 0;
    __syncthreads();
    int stride = gridDim.x * blockDim.x;
    for (int e = blockIdx.x * blockDim.x + t; e < E; e += stride)
        atomicAdd(&hist[col[e] >> BSH], 1);
    __syncthreads();
    for (int i = t; i < NB; i += blockDim.x)
        if (hist[i]) atomicAdd(&gcount[i], hist[i]);
}

// ---------- exclusive scan of bucket counts (1 block of MAXB threads) ----------
__global__ void k_scan(const int* __restrict__ gcount, int* __restrict__ base,
                       int* __restrict__ cursor, int NB) {
    __shared__ int sd[MAXB];
    int t = threadIdx.x;
    int v = (t < NB) ? gcount[t] : 0;
    sd[t] = v;
    __syncthreads();
    for (int o = 1; o < MAXB; o <<= 1) {
        int x = (t >= o) ? sd[t - o] : 0;
        __syncthreads();
        sd[t] += x;
        __syncthreads();
    }
    if (t < NB) {
        int excl = sd[t] - v;
        base[t] = excl;
        cursor[t * 16] = excl;            // 64B-padded cursors
        if (t == NB - 1) base[NB] = sd[t];
    }
}

// ---------- bin edges by target bucket (semi-coalesced writes) ----------
__global__ void k_scatter(const int* __restrict__ row, const int* __restrict__ col,
                          int* __restrict__ cursor, unsigned* __restrict__ bins,
                          int E, int NB, int CHK) {
    __shared__ int hist[MAXB];
    __shared__ int lbase[MAXB];
    int t = threadIdx.x;
    int cb = blockIdx.x * CHK;
    int ce = min(E, cb + CHK);
    for (int i = t; i < MAXB; i += blockDim.x) hist[i] = 0;
    __syncthreads();
    for (int e = cb + t; e < ce; e += blockDim.x)
        atomicAdd(&hist[col[e] >> BSH], 1);
    __syncthreads();
    for (int i = t; i < NB; i += blockDim.x) {
        int h = hist[i];
        lbase[i] = h ? atomicAdd(&cursor[i * 16], h) : 0;
    }
    __syncthreads();
    for (int i = t; i < MAXB; i += blockDim.x) hist[i] = 0;  // reuse as offsets
    __syncthreads();
    for (int e = cb + t; e < ce; e += blockDim.x) {
        int c = col[e];
        int b = c >> BSH;
        int pos = lbase[b] + atomicAdd(&hist[b], 1);
        bins[pos] = (unsigned)row[e] | ((unsigned)(c & (BSZ - 1)) << 18);
    }
}

// ---------- per-bucket degree (LDS int atomics, coalesced write) ----------
__global__ void k_deg(const unsigned* __restrict__ bins, const int* __restrict__ base,
                      int* __restrict__ deg, int N) {
    __shared__ int cnt[BSZ];
    int t = threadIdx.x, b = blockIdx.x;
    for (int i = t; i < BSZ; i += blockDim.x) cnt[i] = 0;
    __syncthreads();
    int s = base[b], e = base[b + 1];
    for (int j = s + t; j < e; j += blockDim.x)
        atomicAdd(&cnt[bins[j] >> 18], 1);
    __syncthreads();
    int nb = b << BSH;
    for (int i = t; i < BSZ; i += blockDim.x) {
        int node = nb + i;
        if (node < N) deg[node] = cnt[i];
    }
}

// ---------- dinv = rsqrt(deg+1); dx = dinv*x ----------
__global__ void k_dinv(const int* __restrict__ deg, const float* __restrict__ x,
                       float* __restrict__ dinv, float* __restrict__ dx, int N) {
    int i = blockIdx.x * blockDim.x + threadIdx.x;
    if (i < N) {
        float d = rsqrtf((float)(deg[i] + 1));
        dinv[i] = d;
        dx[i] = d * x[i];
    }
}

// ---------- per-bucket layer-1 scalar aggregate (LDS fp32 atomics) ----------
__global__ void k_s1(const unsigned* __restrict__ bins, const int* __restrict__ base,
                     const float* __restrict__ dinv, const float* __restrict__ dx,
                     float2* __restrict__ gds, int N) {
    __shared__ float sacc[BSZ];
    int t = threadIdx.x, b = blockIdx.x;
    for (int i = t; i < BSZ; i += blockDim.x) sacc[i] = 0.0f;
    __syncthreads();
    int s = base[b], e = base[b + 1];
    for (int j = s + t; j < e; j += blockDim.x) {
        unsigned rec = bins[j];
        atomicAdd(&sacc[rec >> 18], dx[rec & 0x3FFFFu]);
    }
    __syncthreads();
    int nb = b << BSH;
    for (int i = t; i < BSZ; i += blockDim.x) {
        int node = nb + i;
        if (node < N) {
            float d = dinv[node];
            gds[node] = make_float2(d, d * (sacc[i] + dx[node]));  // + self-loop
        }
    }
}

// ---------- per-bucket layer-2 aggregate in LDS + fused epilogue ----------
__global__ void k_agg(const unsigned* __restrict__ bins, const int* __restrict__ base,
                      const float2* __restrict__ gds,
                      const float* __restrict__ W1, const float* __restrict__ b1,
                      const float* __restrict__ W2, const float* __restrict__ b2,
                      const float* __restrict__ Wfc, const float* __restrict__ bfc,
                      float* __restrict__ out, int N) {
    __shared__ float acc[BSZ * HD];   // 32 KB
    int t = threadIdx.x, b = blockIdx.x;
    for (int i = t; i < BSZ * HD; i += blockDim.x) acc[i] = 0.0f;
    int f = t & (HD - 1);
    int g = t >> 4;                   // 16 groups of 16 lanes; lane f = feature
    float w1 = W1[f], bb1 = b1[f];
    __syncthreads();
    int s = base[b], e = base[b + 1];
    for (int j = s + g; j < e; j += 16) {
        unsigned rec = bins[j];                 // 16 lanes same addr -> 1 req
        float2 dsr = gds[rec & 0x3FFFFu];       // (dinv[r], s1[r])
        float h = fmaxf(fmaf(dsr.y, w1, bb1), 0.0f);
        atomicAdd(&acc[(rec >> 18) * HD + f], dsr.x * h);
    }
    __syncthreads();
    int nb = b << BSH;
    for (int l = t; l < BSZ; l += blockDim.x) {
        int node = nb + l;
        if (node >= N) continue;
        float2 dsi = gds[node];
        float di = dsi.x, si = dsi.y;
        float aggv[HD];
        #pragma unroll
        for (int k = 0; k < HD; ++k) {          // rotated read: 2-way banks only
            int kk = (k + l) & (HD - 1);
            float selfh = fmaxf(fmaf(si, W1[kk], b1[kk]), 0.0f);
            aggv[kk] = di * (acc[l * HD + kk] + di * selfh);
        }
        float o0 = bfc[0], o1 = bfc[1], o2 = bfc[2], o3 = bfc[3];
        #pragma unroll
        for (int f2 = 0; f2 < HD; ++f2) {
            float h = b2[f2];
            #pragma unroll
            for (int k = 0; k < HD; ++k) h = fmaf(aggv[k], W2[k * HD + f2], h);
            h = fmaxf(h, 0.0f);
            o0 = fmaf(h, Wfc[f2 * NC + 0], o0);
            o1 = fmaf(h, Wfc[f2 * NC + 1], o1);
            o2 = fmaf(h, Wfc[f2 * NC + 2], o2);
            o3 = fmaf(h, Wfc[f2 * NC + 3], o3);
        }
        ((float4*)out)[node] = make_float4(o0, o1, o2, o3);
    }
}

extern "C" void kernel_launch(void* const* d_in, const int* in_sizes, int n_in,
                              void* d_out, int out_size, void* d_ws, size_t ws_size,
                              hipStream_t stream) {
    const float* x   = (const float*)d_in[0];
    const int*   ei  = (const int*)d_in[1];
    const float* W1  = (const float*)d_in[2];
    const float* b1  = (const float*)d_in[3];
    const float* W2  = (const float*)d_in[4];
    const float* b2  = (const float*)d_in[5];
    const float* Wfc = (const float*)d_in[6];
    const float* bfc = (const float*)d_in[7];
    float* out = (float*)d_out;

    const int N = in_sizes[0];        // 250000 (< 2^18, fits record packing)
    const int E = in_sizes[1] / 2;    // 4000000
    const int NB = (N + BSZ - 1) / BSZ;  // 489
    const int* row = ei;
    const int* col = ei + E;

    // workspace layout
    char* ws = (char*)d_ws;
    size_t off = 0;
    unsigned* bins = (unsigned*)(ws + off); off += (size_t)E * 4;       // 16MB
    int*    deg   = (int*)(ws + off);    off += (size_t)N * 4;
    float*  dinv  = (float*)(ws + off);  off += (size_t)N * 4;
    float*  dx    = (float*)(ws + off);  off += (size_t)N * 4;
    float2* gds   = (float2*)(ws + off); off += (size_t)N * 8;
    int*    gcount= (int*)(ws + off);    off += (size_t)MAXB * 4;
    int*    bse   = (int*)(ws + off);    off += (size_t)(MAXB + 1) * 4;
    int*    cursor= (int*)(ws + off);    off += (size_t)MAXB * 16 * 4;

    hipMemsetAsync(gcount, 0, (size_t)MAXB * 4, stream);

    const int B = 256;
    k_count<<<512, B, 0, stream>>>(col, gcount, E, NB);
    k_scan<<<1, MAXB, 0, stream>>>(gcount, bse, cursor, NB);
    const int G = 1024;
    const int CHK = (E + G - 1) / G;
    k_scatter<<<G, B, 0, stream>>>(row, col, cursor, bins, E, NB, CHK);
    k_deg<<<NB, B, 0, stream>>>(bins, bse, deg, N);
    k_dinv<<<(N + B - 1) / B, B, 0, stream>>>(deg, x, dinv, dx, N);
    k_s1<<<NB, B, 0, stream>>>(bins, bse, dinv, dx, gds, N);
    k_agg<<<NB, B, 0, stream>>>(bins, bse, gds, W1, b1, W2, b2, Wfc, bfc, out, N);
}